// Round 1
// baseline (11189.841 us; speedup 1.0000x reference)
//
#include <hip/hip_runtime.h>
#include <math.h>

// Problem constants
#define TT   128
#define BSZ  256
#define IDIM 256
#define CDIM 512
#define NN   128
#define MM   64
#define KTOT 832          // IDIM + MM + CDIM
#define GJ   2048         // 4*CDIM gate rows
#define ODIM 576          // CDIM + MM
#define OC   268          // 70 + 198 head outputs

__device__ __forceinline__ float sigmoidf_(float x) { return 1.0f / (1.0f + expf(-x)); }
__device__ __forceinline__ float softplusf_(float x) {
    // log(1+exp(x)) stable
    return (x > 0.f) ? (x + log1pf(expf(-x))) : log1pf(expf(x));
}

// ---------------- prep: pack Wt[k][gj] (k-major) and bias ----------------
__global__ void k_pack(const float* __restrict__ W_ih, const float* __restrict__ W_hh,
                       const float* __restrict__ b_ih, const float* __restrict__ b_hh,
                       float* __restrict__ Wt, float* __restrict__ bias)
{
    const int total = KTOT * GJ + GJ;
    for (int idx = blockIdx.x * 256 + threadIdx.x; idx < total; idx += gridDim.x * 256) {
        if (idx < KTOT * GJ) {
            int k = idx >> 11;        // /2048
            int gj = idx & 2047;
            Wt[idx] = (k < 320) ? W_ih[gj * 320 + k] : W_hh[gj * 512 + (k - 320)];
        } else {
            int j = idx - KTOT * GJ;
            bias[j] = b_ih[j] + b_hh[j];
        }
    }
}

// ---------------- prep: initial state ----------------
__global__ void k_init(const float* __restrict__ hid, const float* __restrict__ c0,
                       const float* __restrict__ mem_bias, const float* __restrict__ r0,
                       float* __restrict__ h0, float* __restrict__ cst, float* __restrict__ mem,
                       float* __restrict__ rdv, float* __restrict__ w_r, float* __restrict__ w_w)
{
    const int A = BSZ * CDIM;              // h
    const int B = A + BSZ * CDIM;          // c
    const int C = B + BSZ * NN * MM;       // mem
    const int D = C + BSZ * MM;            // read
    const int E = D + 2 * BSZ * NN;        // w states
    for (int idx = blockIdx.x * 256 + threadIdx.x; idx < E; idx += gridDim.x * 256) {
        if (idx < A) h0[idx] = hid[idx];
        else if (idx < B) { int i = idx - A; cst[i] = c0[i & (CDIM - 1)]; }
        else if (idx < C) { int i = idx - B; mem[i] = mem_bias[i & (NN * MM - 1)]; }
        else if (idx < D) { int i = idx - C; rdv[i] = r0[i & (MM - 1)]; }
        else { int i = idx - D; if (i < BSZ * NN) w_r[i] = 0.f; else w_w[i - BSZ * NN] = 0.f; }
    }
}

// ---------------- K1: gates GEMM + LSTM epilogue ----------------
// grid (16 j-tiles, 16 b-tiles), 256 threads. Block: 16 b x 32 j x 4 gates.
__global__ __launch_bounds__(256) void k_gates_lstm(
    const float* __restrict__ x_emb,    // inp + t*BSZ*IDIM
    const float* __restrict__ read_v,   // BSZ x MM
    const float* __restrict__ h_in,     // BSZ x CDIM
    const float* __restrict__ Wt,       // KTOT x GJ (k-major)
    const float* __restrict__ bias,     // GJ
    float* __restrict__ c_st,           // BSZ x CDIM (in-place)
    float* __restrict__ h_out,          // BSZ x CDIM
    float* __restrict__ out_t)          // BSZ x ODIM
{
    __shared__ float Xs[16][33];
    __shared__ float Ws[32][128];
    const int tid = threadIdx.x;
    const int tx = tid & 15;
    const int ty = tid >> 4;            // b_local 0..15
    const int j0 = blockIdx.x * 32;
    const int b0 = blockIdx.y * 16;

    float acc[8];
#pragma unroll
    for (int u = 0; u < 8; ++u) acc[u] = 0.f;

    for (int kt = 0; kt < KTOT; kt += 32) {
        // stage X tile: 16 x 32
#pragma unroll
        for (int rep = 0; rep < 2; ++rep) {
            int i = tid + rep * 256;
            int bl = i >> 5, kk = i & 31;
            int k = kt + kk;
            int b = b0 + bl;
            float v;
            if (k < IDIM) v = x_emb[b * IDIM + k];
            else if (k < IDIM + MM) v = read_v[b * MM + (k - IDIM)];
            else v = h_in[b * CDIM + (k - IDIM - MM)];
            Xs[bl][kk] = v;
        }
        // stage W tile: 32 x 128 (4 gates x 32 j)
#pragma unroll
        for (int rep = 0; rep < 16; ++rep) {
            int i = tid + rep * 256;
            int kk = i >> 7, col = i & 127;
            int g = col >> 5, jj = col & 31;
            Ws[kk][col] = Wt[(kt + kk) * GJ + g * 512 + j0 + jj];
        }
        __syncthreads();
#pragma unroll
        for (int kk = 0; kk < 32; ++kk) {
            float xv = Xs[ty][kk];
#pragma unroll
            for (int g = 0; g < 4; ++g) {
                float2 wv = *(const float2*)&Ws[kk][g * 32 + 2 * tx];
                acc[g * 2 + 0] += xv * wv.x;
                acc[g * 2 + 1] += xv * wv.y;
            }
        }
        __syncthreads();
    }

    // LSTM epilogue: this thread owns (b, j0+2tx) and (b, j0+2tx+1), all 4 gates
    const int b = b0 + ty;
#pragma unroll
    for (int p = 0; p < 2; ++p) {
        int j = j0 + 2 * tx + p;
        float gi = acc[0 + p] + bias[0 * 512 + j];
        float gf = acc[2 + p] + bias[1 * 512 + j];
        float gg = acc[4 + p] + bias[2 * 512 + j];
        float go = acc[6 + p] + bias[3 * 512 + j];
        float cn = sigmoidf_(gf) * c_st[b * CDIM + j] + sigmoidf_(gi) * tanhf(gg);
        float hn = sigmoidf_(go) * tanhf(cn);
        c_st[b * CDIM + j] = cn;
        h_out[b * CDIM + j] = hn;
        out_t[b * ODIM + j] = hn;
    }
}

// ---------------- K2: heads GEMM o = h @ [read_W | write_W] + bias ----------------
// grid (5 j-tiles of 64, 16 b-tiles of 16), 256 threads.
__global__ __launch_bounds__(256) void k_heads(
    const float* __restrict__ h,        // BSZ x CDIM
    const float* __restrict__ rW,       // CDIM x 70
    const float* __restrict__ rb,       // 70
    const float* __restrict__ wW,       // CDIM x 198
    const float* __restrict__ wb,       // 198
    float* __restrict__ o_all)          // BSZ x OC
{
    __shared__ float hs[16][512];
    const int tid = threadIdx.x;
    const int jt = blockIdx.x, bt = blockIdx.y;
    const int j = jt * 64 + (tid & 63);
    const int brow = tid >> 6;          // 0..3

    for (int i = tid; i < 16 * 512; i += 256) {
        int bl = i >> 9, k = i & 511;
        hs[bl][k] = h[(bt * 16 + bl) * CDIM + k];
    }
    __syncthreads();

    if (j < OC) {
        const float* Wcol; int stride; float bv;
        if (j < 70) { Wcol = rW + j; stride = 70; bv = rb[j]; }
        else        { Wcol = wW + (j - 70); stride = 198; bv = wb[j - 70]; }
        float a0 = 0.f, a1 = 0.f, a2 = 0.f, a3 = 0.f;
        const float* wp = Wcol;
#pragma unroll 8
        for (int k = 0; k < 512; ++k) {
            float wv = *wp; wp += stride;
            a0 += hs[brow + 0][k] * wv;
            a1 += hs[brow + 4][k] * wv;
            a2 += hs[brow + 8][k] * wv;
            a3 += hs[brow + 12][k] * wv;
        }
        int bb = bt * 16;
        o_all[(bb + brow + 0) * OC + j]  = a0 + bv;
        o_all[(bb + brow + 4) * OC + j]  = a1 + bv;
        o_all[(bb + brow + 8) * OC + j]  = a2 + bv;
        o_all[(bb + brow + 12) * OC + j] = a3 + bv;
    }
}

// ---------------- K3: addressing + read + memory write. One block per b. ----------------
__global__ __launch_bounds__(256) void k_address(
    const float* __restrict__ o_all,    // BSZ x OC
    float* __restrict__ mem,            // BSZ x NN x MM
    float* __restrict__ rdv,            // BSZ x MM
    float* __restrict__ w_r,            // BSZ x NN
    float* __restrict__ w_w,            // BSZ x NN
    float* __restrict__ out_t)          // BSZ x ODIM
{
    const int b = blockIdx.x, tid = threadIdx.x;
    __shared__ float ms[NN * 65];       // stride-65 pad: bank = (n+m)%32
    __shared__ float os[OC];
    __shared__ float wgs[NN];
    __shared__ float wsh[NN];
    __shared__ float red4[4];
    __shared__ float esh[MM], ash[MM];

    for (int i = tid; i < NN * MM; i += 256) {
        int n = i >> 6, m = i & 63;
        ms[n * 65 + m] = mem[(size_t)b * NN * MM + i];
    }
    for (int i = tid; i < OC; i += 256) os[i] = o_all[b * OC + i];
    __syncthreads();

    for (int head = 0; head < 2; ++head) {
        const int ob = head ? 70 : 0;
        const float* wprev = head ? w_w : w_r;
        float* wstore = head ? w_w : w_r;

        // wave-uniform scalars (broadcast LDS reads)
        float beta  = softplusf_(os[ob + 64]);
        float g     = sigmoidf_(os[ob + 65]);
        float s0r = os[ob + 66], s1r = os[ob + 67], s2r = os[ob + 68];
        float smx = fmaxf(s0r, fmaxf(s1r, s2r));
        float e0 = expf(s0r - smx), e1 = expf(s1r - smx), e2 = expf(s2r - smx);
        float einv = 1.f / (e0 + e1 + e2);
        float s0 = e0 * einv, s1 = e1 * einv, s2 = e2 * einv;
        float gamma = 1.f + softplusf_(os[ob + 69]);

        float simv = -1e30f;
        if (tid < NN) {
            float dot = 0.f, nm2 = 0.f, nk2 = 0.f;
            const float* mrow = ms + tid * 65;
#pragma unroll 8
            for (int m = 0; m < MM; ++m) {
                float mv = mrow[m] + 1e-16f;
                float kv = os[ob + m] + 1e-16f;
                dot += mv * kv; nm2 += mv * mv; nk2 += kv * kv;
            }
            float nm = fmaxf(sqrtf(nm2), 1e-8f);
            float nk = fmaxf(sqrtf(nk2), 1e-8f);
            simv = beta * dot / (nm * nk);
        }
        // block max over 128 (idle lanes hold -1e30)
        float v = simv;
#pragma unroll
        for (int off = 32; off; off >>= 1) v = fmaxf(v, __shfl_xor(v, off));
        if ((tid & 63) == 0) red4[tid >> 6] = v;
        __syncthreads();
        float smax = fmaxf(fmaxf(red4[0], red4[1]), fmaxf(red4[2], red4[3]));
        __syncthreads();

        float pv = (tid < NN) ? expf(simv - smax) : 0.f;
        v = pv;
#pragma unroll
        for (int off = 32; off; off >>= 1) v += __shfl_xor(v, off);
        if ((tid & 63) == 0) red4[tid >> 6] = v;
        __syncthreads();
        float psum = red4[0] + red4[1] + red4[2] + red4[3];
        __syncthreads();

        if (tid < NN) {
            float wc = pv / psum;
            wgs[tid] = g * wc + (1.f - g) * wprev[b * NN + tid];
        }
        __syncthreads();

        float wv_ = 0.f;
        if (tid < NN) {
            int nl = (tid + NN - 1) & (NN - 1), nr = (tid + 1) & (NN - 1);
            float wwv = s0 * wgs[nl] + s1 * wgs[tid] + s2 * wgs[nr];
            wv_ = powf(wwv, gamma);
        }
        v = wv_;
#pragma unroll
        for (int off = 32; off; off >>= 1) v += __shfl_xor(v, off);
        if ((tid & 63) == 0) red4[tid >> 6] = v;
        __syncthreads();
        float wsum = red4[0] + red4[1] + red4[2] + red4[3];
        __syncthreads();

        if (tid < NN) {
            float wfin = wv_ / (wsum + 1e-16f);
            wsh[tid] = wfin;
            wstore[b * NN + tid] = wfin;
        }
        __syncthreads();

        if (head == 0) {
            // memory read -> rdv and out
            if (tid < MM) {
                float r = 0.f;
#pragma unroll 8
                for (int n = 0; n < NN; ++n) r += wsh[n] * ms[n * 65 + tid];
                rdv[b * MM + tid] = r;
                out_t[b * ODIM + CDIM + tid] = r;
            }
            __syncthreads();
        } else {
            // memory erase/add update
            if (tid < MM) {
                esh[tid] = sigmoidf_(os[140 + tid]);
                ash[tid] = os[204 + tid];
            }
            __syncthreads();
            for (int i = tid; i < NN * MM; i += 256) {
                int n = i >> 6, m = i & 63;
                float mv = ms[n * 65 + m];
                float wvn = wsh[n];
                mem[(size_t)b * NN * MM + i] = mv * (1.f - wvn * esh[m]) + wvn * ash[m];
            }
            __syncthreads();
        }
    }
}

extern "C" void kernel_launch(void* const* d_in, const int* in_sizes, int n_in,
                              void* d_out, int out_size, void* d_ws, size_t ws_size,
                              hipStream_t stream) {
    const float* inp      = (const float*)d_in[0];
    const float* hid      = (const float*)d_in[1];
    const float* c0       = (const float*)d_in[2];
    const float* mem_bias = (const float*)d_in[3];
    const float* r0       = (const float*)d_in[4];
    const float* W_ih     = (const float*)d_in[5];
    const float* W_hh     = (const float*)d_in[6];
    const float* b_ih     = (const float*)d_in[7];
    const float* b_hh     = (const float*)d_in[8];
    const float* read_W   = (const float*)d_in[9];
    const float* read_b   = (const float*)d_in[10];
    const float* write_W  = (const float*)d_in[11];
    const float* write_b  = (const float*)d_in[12];
    float* out = (float*)d_out;
    float* ws  = (float*)d_ws;

    float* Wt    = ws;                       // 832*2048
    float* bias  = Wt + KTOT * GJ;           // 2048
    float* h0    = bias + GJ;                // 256*512
    float* h1    = h0 + BSZ * CDIM;
    float* cst   = h1 + BSZ * CDIM;
    float* mem   = cst + BSZ * CDIM;         // 256*128*64
    float* rdv   = mem + BSZ * NN * MM;      // 256*64
    float* w_r   = rdv + BSZ * MM;           // 256*128
    float* w_w   = w_r + BSZ * NN;
    float* o_all = w_w + BSZ * NN;           // 256*268

    k_pack<<<2048, 256, 0, stream>>>(W_ih, W_hh, b_ih, b_hh, Wt, bias);
    k_init<<<2048, 256, 0, stream>>>(hid, c0, mem_bias, r0, h0, cst, mem, rdv, w_r, w_w);

    for (int t = 0; t < TT; ++t) {
        const float* hin = (t & 1) ? h1 : h0;
        float* hout      = (t & 1) ? h0 : h1;
        float* out_t = out + (size_t)t * BSZ * ODIM;
        k_gates_lstm<<<dim3(16, 16), 256, 0, stream>>>(
            inp + (size_t)t * BSZ * IDIM, rdv, hin, Wt, bias, cst, hout, out_t);
        k_heads<<<dim3(5, 16), 256, 0, stream>>>(
            hout, read_W, read_b, write_W, write_b, o_all);
        k_address<<<BSZ, 256, 0, stream>>>(o_all, mem, rdv, w_r, w_w, out_t);
    }
}

// Round 2
// 3866.895 us; speedup vs baseline: 2.8938x; 2.8938x over previous
//
#include <hip/hip_runtime.h>
#include <math.h>

#define TT   128
#define BSZ  256
#define IDIM 256
#define CDIM 512
#define NN   128
#define MM   64
#define KTOT 832
#define GJ   2048
#define ODIM 576
#define OC   268

#define NKB1 26            // K-blocks of 32 for gates GEMM (832/32)
#define NJT1 32            // j-tiles of 16 across 512
#define NKB2 16            // K-blocks for heads GEMM (512/32)
#define NJT2 17            // j-tiles of 16 across 272 (268 padded)

typedef __attribute__((ext_vector_type(8))) short s16x8;
typedef __attribute__((ext_vector_type(4))) float f32x4;
#define MFMA __builtin_amdgcn_mfma_f32_16x16x32_bf16

__device__ __forceinline__ float sigmoidf_(float x) { return 1.0f / (1.0f + expf(-x)); }
__device__ __forceinline__ float softplusf_(float x) {
    return (x > 0.f) ? (x + log1pf(expf(-x))) : log1pf(expf(x));
}
__device__ __forceinline__ unsigned short f2bf(float f) {
    unsigned int u = __builtin_bit_cast(unsigned int, f);
    u += 0x7FFFu + ((u >> 16) & 1u);
    return (unsigned short)(u >> 16);
}
__device__ __forceinline__ float bf2f(unsigned short b) {
    unsigned int u = ((unsigned int)b) << 16;
    return __builtin_bit_cast(float, u);
}
__device__ __forceinline__ void split2(float v, unsigned short& h, unsigned short& lo) {
    h = f2bf(v);
    lo = f2bf(v - bf2f(h));
}

// ---------------- prep: pack gates weights into MFMA fragment order, split hi/lo ----------------
// layout: idx = (((kb*32 + jt)*4 + g)*64 + lane)*8 + e ; k = kb*32 + (lane>>4)*8 + e ; col = g*512 + jt*16 + (lane&15)
__global__ void k_packB1(const float* __restrict__ W_ih, const float* __restrict__ W_hh,
                         const float* __restrict__ b_ih, const float* __restrict__ b_hh,
                         unsigned short* __restrict__ Bh, unsigned short* __restrict__ Bl,
                         float* __restrict__ bias)
{
    const int total = NKB1 * NJT1 * 4 * 64 * 8;
    for (int idx = blockIdx.x * 256 + threadIdx.x; idx < total + GJ; idx += gridDim.x * 256) {
        if (idx < total) {
            int e  = idx & 7;
            int l  = (idx >> 3) & 63;
            int g  = (idx >> 9) & 3;
            int jt = (idx >> 11) & 31;
            int kb = idx >> 16;
            int k  = kb * 32 + ((l >> 4) << 3) + e;
            int n  = g * 512 + jt * 16 + (l & 15);
            float v = (k < 320) ? W_ih[n * 320 + k] : W_hh[n * 512 + (k - 320)];
            unsigned short h_, l_;
            split2(v, h_, l_);
            Bh[idx] = h_; Bl[idx] = l_;
        } else {
            int j = idx - total;
            bias[j] = b_ih[j] + b_hh[j];
        }
    }
}

// ---------------- prep: pack head weights, split hi/lo ----------------
__global__ void k_packB2(const float* __restrict__ rW, const float* __restrict__ rb,
                         const float* __restrict__ wW, const float* __restrict__ wb,
                         unsigned short* __restrict__ Bh, unsigned short* __restrict__ Bl,
                         float* __restrict__ bias2)
{
    const int total = NKB2 * NJT2 * 64 * 8;
    for (int idx = blockIdx.x * 256 + threadIdx.x; idx < total + NJT2 * 16; idx += gridDim.x * 256) {
        if (idx < total) {
            int e   = idx & 7;
            int l   = (idx >> 3) & 63;
            int q   = idx >> 9;           // kb*17 + jt
            int jt  = q % 17;
            int kb  = q / 17;
            int k   = kb * 32 + ((l >> 4) << 3) + e;
            int col = jt * 16 + (l & 15);
            float v = 0.f;
            if (col < 70)       v = rW[k * 70 + col];
            else if (col < OC)  v = wW[k * 198 + (col - 70)];
            unsigned short h_, l_;
            split2(v, h_, l_);
            Bh[idx] = h_; Bl[idx] = l_;
        } else {
            int col = idx - total;
            bias2[col] = (col < 70) ? rb[col] : ((col < OC) ? wb[col - 70] : 0.f);
        }
    }
}

// ---------------- prep: initial state ----------------
__global__ void k_init(const float* __restrict__ hid, const float* __restrict__ c0,
                       const float* __restrict__ mem_bias, const float* __restrict__ r0,
                       float* __restrict__ h0, float* __restrict__ cst, float* __restrict__ mem,
                       float* __restrict__ rdv, float* __restrict__ w_r, float* __restrict__ w_w)
{
    const int A = BSZ * CDIM;
    const int B = A + BSZ * CDIM;
    const int C = B + BSZ * NN * MM;
    const int D = C + BSZ * MM;
    const int E = D + 2 * BSZ * NN;
    for (int idx = blockIdx.x * 256 + threadIdx.x; idx < E; idx += gridDim.x * 256) {
        if (idx < A) h0[idx] = hid[idx];
        else if (idx < B) { int i = idx - A; cst[i] = c0[i & (CDIM - 1)]; }
        else if (idx < C) { int i = idx - B; mem[i] = mem_bias[i & (NN * MM - 1)]; }
        else if (idx < D) { int i = idx - C; rdv[i] = r0[i & (MM - 1)]; }
        else { int i = idx - D; if (i < BSZ * NN) w_r[i] = 0.f; else w_w[i - BSZ * NN] = 0.f; }
    }
}

// ---------------- K1: gates GEMM (split-bf16 MFMA) + LSTM epilogue ----------------
// grid (32 jt, 8 mt) x 256 thr. Block tile: 32 rows x (4 gates x 16 j). Split-K over 4 waves.
__global__ __launch_bounds__(256) void k_gates_mfma(
    const float* __restrict__ x_emb, const float* __restrict__ read_v,
    const float* __restrict__ h_in,
    const unsigned short* __restrict__ Bh, const unsigned short* __restrict__ Bl,
    const float* __restrict__ bias,
    float* __restrict__ c_st, float* __restrict__ h_out, float* __restrict__ out_t)
{
    __shared__ __align__(16) unsigned short AH[4][32][40];
    __shared__ __align__(16) unsigned short AL[4][32][40];
    __shared__ float red[4][32][4][16];
    const int tid = threadIdx.x;
    const int w = tid >> 6, l = tid & 63;
    const int jt = blockIdx.x;
    const int m0 = blockIdx.y * 32;

    f32x4 acc[2][4];
#pragma unroll
    for (int s = 0; s < 2; ++s)
#pragma unroll
        for (int g = 0; g < 4; ++g) acc[s][g] = (f32x4){0.f, 0.f, 0.f, 0.f};

    const int row_s = l >> 1;          // 0..31 staged row
    const int c0 = (l & 1) * 16;       // staged col start (floats)
    const int rr = l & 15;
    const int kq = (l >> 4) * 8;

    for (int i = 0; i < 7; ++i) {
        const int kb = i * 4 + w;
        const bool act = (kb < NKB1);
        s16x8 bfh[4], bfl[4];
        if (act) {
            const int boff = ((kb * 32 + jt) * 256 + l) * 8;
#pragma unroll
            for (int g = 0; g < 4; ++g) {
                bfh[g] = *(const s16x8*)(Bh + boff + g * 512);
                bfl[g] = *(const s16x8*)(Bl + boff + g * 512);
            }
            const int kg = kb * 32;
            const float* p;
            if (kb < 8)       p = x_emb + (m0 + row_s) * IDIM + kg + c0;
            else if (kb < 10) p = read_v + (m0 + row_s) * MM + (kg - IDIM) + c0;
            else              p = h_in + (m0 + row_s) * CDIM + (kg - 320) + c0;
            float f[16];
            *(float4*)&f[0]  = ((const float4*)p)[0];
            *(float4*)&f[4]  = ((const float4*)p)[1];
            *(float4*)&f[8]  = ((const float4*)p)[2];
            *(float4*)&f[12] = ((const float4*)p)[3];
            s16x8 vh0, vl0, vh1, vl1;
#pragma unroll
            for (int q = 0; q < 8; ++q) {
                unsigned short h_, l_;
                split2(f[q], h_, l_);
                vh0[q] = (short)h_; vl0[q] = (short)l_;
                split2(f[8 + q], h_, l_);
                vh1[q] = (short)h_; vl1[q] = (short)l_;
            }
            *(s16x8*)&AH[w][row_s][c0]     = vh0;
            *(s16x8*)&AH[w][row_s][c0 + 8] = vh1;
            *(s16x8*)&AL[w][row_s][c0]     = vl0;
            *(s16x8*)&AL[w][row_s][c0 + 8] = vl1;
        }
        __syncthreads();
        if (act) {
            s16x8 a0h = *(const s16x8*)&AH[w][rr][kq];
            s16x8 a0l = *(const s16x8*)&AL[w][rr][kq];
            s16x8 a1h = *(const s16x8*)&AH[w][16 + rr][kq];
            s16x8 a1l = *(const s16x8*)&AL[w][16 + rr][kq];
#pragma unroll
            for (int g = 0; g < 4; ++g) {
                acc[0][g] = MFMA(a0h, bfh[g], acc[0][g], 0, 0, 0);
                acc[1][g] = MFMA(a1h, bfh[g], acc[1][g], 0, 0, 0);
                acc[0][g] = MFMA(a0l, bfh[g], acc[0][g], 0, 0, 0);
                acc[1][g] = MFMA(a1l, bfh[g], acc[1][g], 0, 0, 0);
                acc[0][g] = MFMA(a0h, bfl[g], acc[0][g], 0, 0, 0);
                acc[1][g] = MFMA(a1h, bfl[g], acc[1][g], 0, 0, 0);
            }
        }
        __syncthreads();
    }

    // split-K reduction + LSTM epilogue
#pragma unroll
    for (int s = 0; s < 2; ++s)
#pragma unroll
        for (int g = 0; g < 4; ++g)
#pragma unroll
            for (int r = 0; r < 4; ++r)
                red[w][s * 16 + (l >> 4) * 4 + r][g][l & 15] = acc[s][g][r];
    __syncthreads();
    const int j = tid & 15, r0 = tid >> 4;
#pragma unroll
    for (int s = 0; s < 2; ++s) {
        const int row = s * 16 + r0;
        const int b = m0 + row;
        const int jg = jt * 16 + j;
        float gv0 = red[0][row][0][j] + red[1][row][0][j] + red[2][row][0][j] + red[3][row][0][j];
        float gv1 = red[0][row][1][j] + red[1][row][1][j] + red[2][row][1][j] + red[3][row][1][j];
        float gv2 = red[0][row][2][j] + red[1][row][2][j] + red[2][row][2][j] + red[3][row][2][j];
        float gv3 = red[0][row][3][j] + red[1][row][3][j] + red[2][row][3][j] + red[3][row][3][j];
        float gi = gv0 + bias[jg];
        float gf = gv1 + bias[512 + jg];
        float gg = gv2 + bias[1024 + jg];
        float go = gv3 + bias[1536 + jg];
        float cn = sigmoidf_(gf) * c_st[b * CDIM + jg] + sigmoidf_(gi) * tanhf(gg);
        float hn = sigmoidf_(go) * tanhf(cn);
        c_st[b * CDIM + jg] = cn;
        h_out[b * CDIM + jg] = hn;
        out_t[b * ODIM + jg] = hn;
    }
}

// ---------------- K2: heads GEMM (split-bf16 MFMA) ----------------
// grid (17 jt, 16 mt) x 256 thr. Block tile: 16 rows x 16 cols. Split-K over 4 waves (16 kb).
__global__ __launch_bounds__(256) void k_heads_mfma(
    const float* __restrict__ h,
    const unsigned short* __restrict__ Bh, const unsigned short* __restrict__ Bl,
    const float* __restrict__ bias2, float* __restrict__ o_all)
{
    __shared__ __align__(16) unsigned short AH[4][16][40];
    __shared__ __align__(16) unsigned short AL[4][16][40];
    __shared__ float red[4][16][16];
    const int tid = threadIdx.x;
    const int w = tid >> 6, l = tid & 63;
    const int jt = blockIdx.x;
    const int m0 = blockIdx.y * 16;

    f32x4 acc = (f32x4){0.f, 0.f, 0.f, 0.f};
    const int row_s = l >> 2;        // 0..15
    const int c0 = (l & 3) * 8;      // 0,8,16,24
    const int rr = l & 15;
    const int kq = (l >> 4) * 8;

    for (int i = 0; i < 4; ++i) {
        const int kb = i * 4 + w;
        const int boff = ((kb * NJT2 + jt) * 64 + l) * 8;
        s16x8 bh = *(const s16x8*)(Bh + boff);
        s16x8 bl = *(const s16x8*)(Bl + boff);
        const float* p = h + (m0 + row_s) * CDIM + kb * 32 + c0;
        float f[8];
        *(float4*)&f[0] = ((const float4*)p)[0];
        *(float4*)&f[4] = ((const float4*)p)[1];
        s16x8 vh, vl;
#pragma unroll
        for (int q = 0; q < 8; ++q) {
            unsigned short h_, l_;
            split2(f[q], h_, l_);
            vh[q] = (short)h_; vl[q] = (short)l_;
        }
        *(s16x8*)&AH[w][row_s][c0] = vh;
        *(s16x8*)&AL[w][row_s][c0] = vl;
        __syncthreads();
        s16x8 ah = *(const s16x8*)&AH[w][rr][kq];
        s16x8 al = *(const s16x8*)&AL[w][rr][kq];
        acc = MFMA(ah, bh, acc, 0, 0, 0);
        acc = MFMA(al, bh, acc, 0, 0, 0);
        acc = MFMA(ah, bl, acc, 0, 0, 0);
        __syncthreads();
    }
#pragma unroll
    for (int r = 0; r < 4; ++r)
        red[w][(l >> 4) * 4 + r][l & 15] = acc[r];
    __syncthreads();
    const int j = tid & 15, row = tid >> 4;
    const int col = jt * 16 + j;
    if (col < OC) {
        float o = red[0][row][j] + red[1][row][j] + red[2][row][j] + red[3][row][j] + bias2[col];
        o_all[(m0 + row) * OC + col] = o;
    }
}

// ---------------- K3: addressing + read + memory write. One block per b. ----------------
__global__ __launch_bounds__(256) void k_address(
    const float* __restrict__ o_all,
    float* __restrict__ mem,
    float* __restrict__ rdv,
    float* __restrict__ w_r,
    float* __restrict__ w_w,
    float* __restrict__ out_t)
{
    const int b = blockIdx.x, tid = threadIdx.x;
    __shared__ float ms[NN * 65];
    __shared__ float os[OC];
    __shared__ float wgs[NN];
    __shared__ float wsh[NN];
    __shared__ float red4[4];
    __shared__ float esh[MM], ash[MM];

    for (int i = tid; i < NN * MM / 4; i += 256) {
        int n = i >> 4, m4 = (i & 15) * 4;
        float4 v = *(const float4*)&mem[(size_t)b * NN * MM + n * MM + m4];
        ms[n * 65 + m4 + 0] = v.x;
        ms[n * 65 + m4 + 1] = v.y;
        ms[n * 65 + m4 + 2] = v.z;
        ms[n * 65 + m4 + 3] = v.w;
    }
    for (int i = tid; i < OC; i += 256) os[i] = o_all[b * OC + i];
    __syncthreads();

    for (int head = 0; head < 2; ++head) {
        const int ob = head ? 70 : 0;
        const float* wprev = head ? w_w : w_r;
        float* wstore = head ? w_w : w_r;

        float beta  = softplusf_(os[ob + 64]);
        float g     = sigmoidf_(os[ob + 65]);
        float s0r = os[ob + 66], s1r = os[ob + 67], s2r = os[ob + 68];
        float smx = fmaxf(s0r, fmaxf(s1r, s2r));
        float e0 = expf(s0r - smx), e1 = expf(s1r - smx), e2 = expf(s2r - smx);
        float einv = 1.f / (e0 + e1 + e2);
        float s0 = e0 * einv, s1 = e1 * einv, s2 = e2 * einv;
        float gamma = 1.f + softplusf_(os[ob + 69]);

        float simv = -1e30f;
        if (tid < NN) {
            float dot = 0.f, nm2 = 0.f, nk2 = 0.f;
            const float* mrow = ms + tid * 65;
#pragma unroll 8
            for (int m = 0; m < MM; ++m) {
                float mv = mrow[m] + 1e-16f;
                float kv = os[ob + m] + 1e-16f;
                dot += mv * kv; nm2 += mv * mv; nk2 += kv * kv;
            }
            float nm = fmaxf(sqrtf(nm2), 1e-8f);
            float nk = fmaxf(sqrtf(nk2), 1e-8f);
            simv = beta * dot / (nm * nk);
        }
        float v = simv;
#pragma unroll
        for (int off = 32; off; off >>= 1) v = fmaxf(v, __shfl_xor(v, off));
        if ((tid & 63) == 0) red4[tid >> 6] = v;
        __syncthreads();
        float smax = fmaxf(fmaxf(red4[0], red4[1]), fmaxf(red4[2], red4[3]));
        __syncthreads();

        float pv = (tid < NN) ? expf(simv - smax) : 0.f;
        v = pv;
#pragma unroll
        for (int off = 32; off; off >>= 1) v += __shfl_xor(v, off);
        if ((tid & 63) == 0) red4[tid >> 6] = v;
        __syncthreads();
        float psum = red4[0] + red4[1] + red4[2] + red4[3];
        __syncthreads();

        if (tid < NN) {
            float wc = pv / psum;
            wgs[tid] = g * wc + (1.f - g) * wprev[b * NN + tid];
        }
        __syncthreads();

        float wv_ = 0.f;
        if (tid < NN) {
            int nl = (tid + NN - 1) & (NN - 1), nr = (tid + 1) & (NN - 1);
            float wwv = s0 * wgs[nl] + s1 * wgs[tid] + s2 * wgs[nr];
            wv_ = powf(wwv, gamma);
        }
        v = wv_;
#pragma unroll
        for (int off = 32; off; off >>= 1) v += __shfl_xor(v, off);
        if ((tid & 63) == 0) red4[tid >> 6] = v;
        __syncthreads();
        float wsum = red4[0] + red4[1] + red4[2] + red4[3];
        __syncthreads();

        if (tid < NN) {
            float wfin = wv_ / (wsum + 1e-16f);
            wsh[tid] = wfin;
            wstore[b * NN + tid] = wfin;
        }
        __syncthreads();

        if (head == 0) {
            if (tid < MM) {
                float r = 0.f;
#pragma unroll 8
                for (int n = 0; n < NN; ++n) r += wsh[n] * ms[n * 65 + tid];
                rdv[b * MM + tid] = r;
                out_t[b * ODIM + CDIM + tid] = r;
            }
            __syncthreads();
        } else {
            if (tid < MM) {
                esh[tid] = sigmoidf_(os[140 + tid]);
                ash[tid] = os[204 + tid];
            }
            __syncthreads();
            for (int i = tid; i < NN * MM / 4; i += 256) {
                int n = i >> 4, m4 = (i & 15) * 4;
                float wvn = wsh[n];
                float4 r;
                r.x = ms[n * 65 + m4 + 0] * (1.f - wvn * esh[m4 + 0]) + wvn * ash[m4 + 0];
                r.y = ms[n * 65 + m4 + 1] * (1.f - wvn * esh[m4 + 1]) + wvn * ash[m4 + 1];
                r.z = ms[n * 65 + m4 + 2] * (1.f - wvn * esh[m4 + 2]) + wvn * ash[m4 + 2];
                r.w = ms[n * 65 + m4 + 3] * (1.f - wvn * esh[m4 + 3]) + wvn * ash[m4 + 3];
                *(float4*)&mem[(size_t)b * NN * MM + n * MM + m4] = r;
            }
            __syncthreads();
        }
    }
}

extern "C" void kernel_launch(void* const* d_in, const int* in_sizes, int n_in,
                              void* d_out, int out_size, void* d_ws, size_t ws_size,
                              hipStream_t stream) {
    const float* inp      = (const float*)d_in[0];
    const float* hid      = (const float*)d_in[1];
    const float* c0       = (const float*)d_in[2];
    const float* mem_bias = (const float*)d_in[3];
    const float* r0       = (const float*)d_in[4];
    const float* W_ih     = (const float*)d_in[5];
    const float* W_hh     = (const float*)d_in[6];
    const float* b_ih     = (const float*)d_in[7];
    const float* b_hh     = (const float*)d_in[8];
    const float* read_W   = (const float*)d_in[9];
    const float* read_b   = (const float*)d_in[10];
    const float* write_W  = (const float*)d_in[11];
    const float* write_b  = (const float*)d_in[12];
    float* out = (float*)d_out;

    char* p = (char*)d_ws;
    auto alloc = [&](size_t bytes) { char* r = p; p += (bytes + 255) & ~(size_t)255; return r; };
    const size_t nB1 = (size_t)NKB1 * NJT1 * 4 * 64 * 8;
    const size_t nB2 = (size_t)NKB2 * NJT2 * 64 * 8;
    unsigned short* B1h = (unsigned short*)alloc(nB1 * 2);
    unsigned short* B1l = (unsigned short*)alloc(nB1 * 2);
    unsigned short* B2h = (unsigned short*)alloc(nB2 * 2);
    unsigned short* B2l = (unsigned short*)alloc(nB2 * 2);
    float* bias1 = (float*)alloc(GJ * 4);
    float* bias2 = (float*)alloc(NJT2 * 16 * 4);
    float* h0    = (float*)alloc((size_t)BSZ * CDIM * 4);
    float* h1    = (float*)alloc((size_t)BSZ * CDIM * 4);
    float* cst   = (float*)alloc((size_t)BSZ * CDIM * 4);
    float* mem   = (float*)alloc((size_t)BSZ * NN * MM * 4);
    float* rdv   = (float*)alloc((size_t)BSZ * MM * 4);
    float* w_r   = (float*)alloc((size_t)BSZ * NN * 4);
    float* w_w   = (float*)alloc((size_t)BSZ * NN * 4);
    float* o_all = (float*)alloc((size_t)BSZ * OC * 4);

    k_packB1<<<4096, 256, 0, stream>>>(W_ih, W_hh, b_ih, b_hh, B1h, B1l, bias1);
    k_packB2<<<600, 256, 0, stream>>>(read_W, read_b, write_W, write_b, B2h, B2l, bias2);
    k_init<<<2048, 256, 0, stream>>>(hid, c0, mem_bias, r0, h0, cst, mem, rdv, w_r, w_w);

    for (int t = 0; t < TT; ++t) {
        const float* hin = (t & 1) ? h1 : h0;
        float* hout      = (t & 1) ? h0 : h1;
        float* out_t = out + (size_t)t * BSZ * ODIM;
        k_gates_mfma<<<dim3(NJT1, 8), 256, 0, stream>>>(
            inp + (size_t)t * BSZ * IDIM, rdv, hin, B1h, B1l, bias1, cst, hout, out_t);
        k_heads_mfma<<<dim3(NJT2, 16), 256, 0, stream>>>(
            hout, B2h, B2l, bias2, o_all);
        k_address<<<BSZ, 256, 0, stream>>>(o_all, mem, rdv, w_r, w_w, out_t);
    }
}